// Round 2
// baseline (422.920 us; speedup 1.0000x reference)
//
#include <hip/hip_runtime.h>
#include <hip/hip_bf16.h>
#include <math.h>

typedef __attribute__((ext_vector_type(8))) __bf16 bf16x8;
typedef __attribute__((ext_vector_type(4))) short short4v;
typedef __attribute__((ext_vector_type(4))) float f32x4;
typedef __attribute__((ext_vector_type(4))) unsigned short ushort4v;

#define LOG2E 1.44269504088896340736f

static __device__ __forceinline__ unsigned short f2bf(float f) {
  unsigned int u = __float_as_uint(f);
  return (unsigned short)((u + 0x7fffu + ((u >> 16) & 1u)) >> 16);
}

static __device__ __forceinline__ void gload16(const unsigned short* g, void* l) {
  __builtin_amdgcn_global_load_lds(
      (const __attribute__((address_space(1))) unsigned int*)g,
      (__attribute__((address_space(3))) unsigned int*)l, 16, 0, 0);
}

// ---------------- cast f32 -> bf16, 4 elems/thread ----------------
__global__ __launch_bounds__(256) void cast4_kernel(const float* __restrict__ in,
                                                    unsigned short* __restrict__ out, int n4) {
  int i = blockIdx.x * 256 + threadIdx.x;
  if (i >= n4) return;
  float4 v = reinterpret_cast<const float4*>(in)[i];
  ushort4v o;
  o.x = f2bf(v.x); o.y = f2bf(v.y); o.z = f2bf(v.z); o.w = f2bf(v.w);
  reinterpret_cast<ushort4v*>(out)[i] = o;
}

// ---------------- RoPE cos/sin table: tab[s*64 + i] = cos, tab[s*64+32+i] = sin ----------------
__global__ __launch_bounds__(256) void tab_kernel(float* __restrict__ tab) {
  int i = blockIdx.x * 256 + threadIdx.x;  // 65536 = 2048 * 32
  int s = i >> 5, d = i & 31;
  float invf = powf(10000.f, -(float)d / 32.f);
  float fr = (float)s * invf;
  tab[s * 64 + d] = cosf(fr);
  tab[s * 64 + 32 + d] = sinf(fr);
}

// ---------------- bf16 GEMM: C[M,N] f32 = A[M,K] * B[N,K]^T ----------------
// 128x128 tile, BK=64, 256 threads (4 waves, 2x2), each wave 64x64 via 4x4 16x16x32 frags.
__global__ __launch_bounds__(256) void gemm_bt_kernel(
    const unsigned short* __restrict__ A, const unsigned short* __restrict__ B,
    float* __restrict__ C, int M, int N, int K, int nbn) {
  __shared__ unsigned short sA[128 * 64];
  __shared__ unsigned short sB[128 * 64];
  const int t = threadIdx.x;
  const int lane = t & 63;
  const int w = t >> 6;
  const int bm = blockIdx.x / nbn, bn = blockIdx.x % nbn;
  const long m0 = (long)bm * 128, n0 = (long)bn * 128;
  const int wm = (w >> 1) * 64, wn = (w & 1) * 64;
  const int lr = lane & 15, lg = lane >> 4;
  f32x4 acc[4][4];
#pragma unroll
  for (int i = 0; i < 4; i++)
#pragma unroll
    for (int j = 0; j < 4; j++) acc[i][j] = (f32x4){0.f, 0.f, 0.f, 0.f};

  for (int k0 = 0; k0 < K; k0 += 64) {
#pragma unroll
    for (int i = 0; i < 4; i++) {
      int chunk = i * 256 + t;          // 0..1023 -> 16KB tile
      int r = chunk >> 3;               // row 0..127
      int c = (chunk & 7) << 3;         // col 0,8,..,56
      gload16(A + (m0 + r) * (long)K + k0 + c, (char*)sA + chunk * 16);
      gload16(B + (n0 + r) * (long)K + k0 + c, (char*)sB + chunk * 16);
    }
    __syncthreads();
#pragma unroll
    for (int kk = 0; kk < 2; ++kk) {
      bf16x8 af[4], bfr[4];
#pragma unroll
      for (int m = 0; m < 4; m++)
        af[m] = *(const bf16x8*)&sA[(wm + m * 16 + lr) * 64 + kk * 32 + lg * 8];
#pragma unroll
      for (int n = 0; n < 4; n++)
        bfr[n] = *(const bf16x8*)&sB[(wn + n * 16 + lr) * 64 + kk * 32 + lg * 8];
#pragma unroll
      for (int m = 0; m < 4; m++)
#pragma unroll
        for (int n = 0; n < 4; n++)
          acc[m][n] = __builtin_amdgcn_mfma_f32_16x16x32_bf16(af[m], bfr[n], acc[m][n], 0, 0, 0);
    }
    __syncthreads();
  }
  // epilogue: D row = 4*(l>>4)+j, col = l&15 (measured layout, m89/m91)
#pragma unroll
  for (int m = 0; m < 4; m++) {
#pragma unroll
    for (int n = 0; n < 4; n++) {
      long col = n0 + wn + n * 16 + lr;
#pragma unroll
      for (int j = 0; j < 4; j++) {
        long row = m0 + wm + m * 16 + lg * 4 + j;
        C[row * N + col] = acc[m][n][j];
      }
    }
  }
}

// ---------------- RMSNorm + RoPE + gain + pack to bf16 ----------------
// one wave per (row, unit): units 0..15 q heads, 16..19 k heads, 20..23 v heads
__global__ __launch_bounds__(256) void pack_kernel(
    const float* __restrict__ qkv, const float* __restrict__ tab,
    const float* __restrict__ qg,
    unsigned short* __restrict__ qb, unsigned short* __restrict__ kb,
    unsigned short* __restrict__ vtb) {
  const int wid = (blockIdx.x * 256 + threadIdx.x) >> 6;
  const int lane = threadIdx.x & 63;
  const int row = wid / 24;      // b*2048 + s
  const int u = wid % 24;
  const int b = row >> 11, s = row & 2047;
  float v;
  if (u < 16)      v = qkv[(size_t)row * 1536 + u * 64 + lane];
  else if (u < 20) v = qkv[(size_t)row * 1536 + 1024 + (u - 16) * 64 + lane];
  else             v = qkv[(size_t)row * 1536 + 1280 + (u - 20) * 64 + lane];
  if (u < 20) {
    float ss = v * v;
#pragma unroll
    for (int m = 32; m >= 1; m >>= 1) ss += __shfl_xor(ss, m);
    float n = v * rsqrtf(ss * (1.0f / 64.0f) + 1.1920929e-07f);
    int i = lane & 31;
    float c = tab[s * 64 + i], sn = tab[s * 64 + 32 + i];
    float p = __shfl_xor(n, 32);
    float o = (lane < 32) ? (n * c + p * sn) : (n * c - p * sn);
    if (u < 16) {
      o *= qg[u];
      qb[((size_t)(b * 16 + u) * 2048 + s) * 64 + lane] = f2bf(o);
    } else {
      kb[((size_t)(b * 4 + (u - 16)) * 2048 + s) * 64 + lane] = f2bf(o);
    }
  } else {
    int hk = u - 20;
    vtb[((size_t)(b * 4 + hk) * 64 + lane) * 2048 + s] = f2bf(v);  // V transposed [64][S]
  }
}

// ---------------- causal flash attention ----------------
// 1 wave = 16 q rows; KV tiles of 16; swapped QK^T so P^T chains into 16x16x16 PV with no shuffles.
__global__ __launch_bounds__(256) void attn_kernel(
    const unsigned short* __restrict__ qb, const unsigned short* __restrict__ kb,
    const unsigned short* __restrict__ vtb, unsigned short* __restrict__ yb) {
  const int lane = threadIdx.x & 63;
  const int w = threadIdx.x >> 6;
  const int idx = blockIdx.x;            // 1024 = B*H*(S/64)
  const int qt = idx & 31;
  const int bh = idx >> 5;
  const int h = bh & 15;
  const int b = bh >> 4;
  const int q0 = qt * 64 + w * 16;
  const unsigned short* Q = qb + (size_t)(b * 16 + h) * 2048 * 64;
  const unsigned short* K = kb + (size_t)(b * 4 + (h >> 2)) * 2048 * 64;
  const unsigned short* V = vtb + (size_t)(b * 4 + (h >> 2)) * 64 * 2048;
  const int qc = lane & 15;
  const int g = lane >> 4;
  const int qrow = q0 + qc;
  const bf16x8 qf0 = *(const bf16x8*)(Q + qrow * 64 + g * 8);
  const bf16x8 qf1 = *(const bf16x8*)(Q + qrow * 64 + 32 + g * 8);
  f32x4 acc[4];
  acc[0] = acc[1] = acc[2] = acc[3] = (f32x4){0.f, 0.f, 0.f, 0.f};
  float m_run = -1e30f, l_run = 0.f;
  const int nt = (q0 >> 4) + 1;
  for (int t = 0; t < nt; ++t) {
    const int kv0 = t << 4;
    const unsigned short* Kt = K + kv0 * 64;
    bf16x8 kf0 = *(const bf16x8*)(Kt + qc * 64 + g * 8);
    bf16x8 kf1 = *(const bf16x8*)(Kt + qc * 64 + 32 + g * 8);
    f32x4 st = (f32x4){0.f, 0.f, 0.f, 0.f};
    st = __builtin_amdgcn_mfma_f32_16x16x32_bf16(kf0, qf0, st, 0, 0, 0);  // S^T: row=kv=4g+j, col=q=qc
    st = __builtin_amdgcn_mfma_f32_16x16x32_bf16(kf1, qf1, st, 0, 0, 0);
    float s[4];
#pragma unroll
    for (int j = 0; j < 4; ++j) s[j] = st[j] * 0.125f;
    if (t == nt - 1) {                // only the diagonal tile needs masking
#pragma unroll
      for (int j = 0; j < 4; ++j)
        if (kv0 + g * 4 + j > qrow) s[j] = -1e30f;
    }
    float mt = fmaxf(fmaxf(s[0], s[1]), fmaxf(s[2], s[3]));
    mt = fmaxf(mt, __shfl_xor(mt, 16));
    mt = fmaxf(mt, __shfl_xor(mt, 32));
    const float m_new = fmaxf(m_run, mt);
    const float corr = exp2f((m_run - m_new) * LOG2E);
    float p[4], ts = 0.f;
#pragma unroll
    for (int j = 0; j < 4; ++j) { p[j] = exp2f((s[j] - m_new) * LOG2E); ts += p[j]; }
    ts += __shfl_xor(ts, 16);
    ts += __shfl_xor(ts, 32);
    l_run = l_run * corr + ts;
    m_run = m_new;
    short4v pb;
#pragma unroll
    for (int j = 0; j < 4; ++j) pb[j] = (short)f2bf(p[j]);
#pragma unroll
    for (int d = 0; d < 4; ++d) {
#pragma unroll
      for (int j = 0; j < 4; ++j) acc[d][j] *= corr;
    }
    const unsigned short* Vt = V + kv0 + g * 4;
#pragma unroll
    for (int d = 0; d < 4; ++d) {
      short4v vf = *(const short4v*)(Vt + (size_t)(d * 16 + qc) * 2048);
      acc[d] = __builtin_amdgcn_mfma_f32_16x16x16bf16_1k(vf, pb, acc[d], 0, 0, 0);  // Y^T += V^T * P^T
    }
  }
  const float inv = 1.0f / l_run;
  unsigned short* Y = yb + (size_t)(b * 2048 + qrow) * 1024 + h * 64;
#pragma unroll
  for (int d = 0; d < 4; ++d)
#pragma unroll
    for (int j = 0; j < 4; ++j)
      Y[d * 16 + g * 4 + j] = f2bf(acc[d][j] * inv);
}

extern "C" void kernel_launch(void* const* d_in, const int* in_sizes, int n_in,
                              void* d_out, int out_size, void* d_ws, size_t ws_size,
                              hipStream_t stream) {
  const float* x  = (const float*)d_in[0];
  const float* Wq = (const float*)d_in[1];
  const float* Wk = (const float*)d_in[2];
  const float* Wv = (const float*)d_in[3];
  const float* Wo = (const float*)d_in[4];
  const float* qg = (const float*)d_in[5];
  float* out = (float*)d_out;

  // workspace layout (bytes)
  char* ws = (char*)d_ws;
  const size_t NEED = 60293120;
  if (ws_size < NEED) return;
  unsigned short* xb   = (unsigned short*)(ws);                 // 8,388,608
  unsigned short* wqkv = (unsigned short*)(ws + 8388608);       // 3,145,728 (Wq|Wk|Wv rows)
  unsigned short* wo_b = (unsigned short*)(ws + 11534336);      // 2,097,152
  float*          qkvf = (float*)        (ws + 13631488);       // 25,165,824
  unsigned short* qbuf = (unsigned short*)(ws + 38797312);      // 8,388,608
  unsigned short* kbuf = (unsigned short*)(ws + 47185920);      // 2,097,152
  unsigned short* vtb  = (unsigned short*)(ws + 49283072);      // 2,097,152
  unsigned short* ybuf = (unsigned short*)(ws + 51380224);      // 8,388,608
  float*          tab  = (float*)        (ws + 59768832);       // 524,288

  // 1. casts
  cast4_kernel<<<4096, 256, 0, stream>>>(x, xb, 1048576);
  cast4_kernel<<<1024, 256, 0, stream>>>(Wq, wqkv, 262144);
  cast4_kernel<<<256, 256, 0, stream>>>(Wk, wqkv + 1048576, 65536);
  cast4_kernel<<<256, 256, 0, stream>>>(Wv, wqkv + 1310720, 65536);
  cast4_kernel<<<1024, 256, 0, stream>>>(Wo, wo_b, 262144);
  tab_kernel<<<256, 256, 0, stream>>>(tab);
  // 2. qkv = x @ Wqkv^T   [4096,1536]
  gemm_bt_kernel<<<32 * 12, 256, 0, stream>>>(xb, wqkv, qkvf, 4096, 1536, 1024, 12);
  // 3. rmsnorm + rope + gain + pack
  pack_kernel<<<24576, 256, 0, stream>>>(qkvf, tab, qg, qbuf, kbuf, vtb);
  // 4. causal flash attention
  attn_kernel<<<1024, 256, 0, stream>>>(qbuf, kbuf, vtb, ybuf);
  // 5. out = y @ Wo^T   [4096,1024]
  gemm_bt_kernel<<<32 * 8, 256, 0, stream>>>(ybuf, wo_b, out, 4096, 1024, 1024, 8);
}

// Round 3
// 140.144 us; speedup vs baseline: 3.0178x; 3.0178x over previous
//
#include <hip/hip_runtime.h>
#include <hip/hip_bf16.h>
#include <math.h>

typedef __attribute__((ext_vector_type(8))) __bf16 bf16x8;
typedef __attribute__((ext_vector_type(4))) short short4v;
typedef __attribute__((ext_vector_type(4))) float f32x4;
typedef __attribute__((ext_vector_type(4))) unsigned short ushort4v;

#define LOG2E 1.44269504088896340736f

static __device__ __forceinline__ unsigned short f2bf(float f) {
  unsigned int u = __float_as_uint(f);
  return (unsigned short)((u + 0x7fffu + ((u >> 16) & 1u)) >> 16);
}
static __device__ __forceinline__ short bfbits(float f) {
  __bf16 h = (__bf16)f;
  return __builtin_bit_cast(short, h);
}

static __device__ __forceinline__ void gload16(const unsigned short* g, void* l) {
  __builtin_amdgcn_global_load_lds(
      (const __attribute__((address_space(1))) unsigned int*)g,
      (__attribute__((address_space(3))) unsigned int*)l, 16, 0, 0);
}

// ---------------- cast f32 -> bf16, 4 elems/thread ----------------
__global__ __launch_bounds__(256) void cast4_kernel(const float* __restrict__ in,
                                                    unsigned short* __restrict__ out, int n4) {
  int i = blockIdx.x * 256 + threadIdx.x;
  if (i >= n4) return;
  float4 v = reinterpret_cast<const float4*>(in)[i];
  ushort4v o;
  o.x = f2bf(v.x); o.y = f2bf(v.y); o.z = f2bf(v.z); o.w = f2bf(v.w);
  reinterpret_cast<ushort4v*>(out)[i] = o;
}

// ---------------- RoPE cos/sin table ----------------
__global__ __launch_bounds__(256) void tab_kernel(float* __restrict__ tab) {
  int i = blockIdx.x * 256 + threadIdx.x;  // 65536 = 2048 * 32
  int s = i >> 5, d = i & 31;
  float invf = powf(10000.f, -(float)d / 32.f);
  float fr = (float)s * invf;
  tab[s * 64 + d] = cosf(fr);
  tab[s * 64 + 32 + d] = sinf(fr);
}

// ---------------- bf16 GEMM: C[M,N] f32 = A[M,K] * B[N,K]^T ----------------
__global__ __launch_bounds__(256) void gemm_bt_kernel(
    const unsigned short* __restrict__ A, const unsigned short* __restrict__ B,
    float* __restrict__ C, int M, int N, int K, int nbn) {
  __shared__ unsigned short sA[128 * 64];
  __shared__ unsigned short sB[128 * 64];
  const int t = threadIdx.x;
  const int lane = t & 63;
  const int w = t >> 6;
  const int bm = blockIdx.x / nbn, bn = blockIdx.x % nbn;
  const long m0 = (long)bm * 128, n0 = (long)bn * 128;
  const int wm = (w >> 1) * 64, wn = (w & 1) * 64;
  const int lr = lane & 15, lg = lane >> 4;
  f32x4 acc[4][4];
#pragma unroll
  for (int i = 0; i < 4; i++)
#pragma unroll
    for (int j = 0; j < 4; j++) acc[i][j] = (f32x4){0.f, 0.f, 0.f, 0.f};

  for (int k0 = 0; k0 < K; k0 += 64) {
#pragma unroll
    for (int i = 0; i < 4; i++) {
      int chunk = i * 256 + t;
      int r = chunk >> 3;
      int c = (chunk & 7) << 3;
      gload16(A + (m0 + r) * (long)K + k0 + c, (char*)sA + chunk * 16);
      gload16(B + (n0 + r) * (long)K + k0 + c, (char*)sB + chunk * 16);
    }
    __syncthreads();
#pragma unroll
    for (int kk = 0; kk < 2; ++kk) {
      bf16x8 af[4], bfr[4];
#pragma unroll
      for (int m = 0; m < 4; m++)
        af[m] = *(const bf16x8*)&sA[(wm + m * 16 + lr) * 64 + kk * 32 + lg * 8];
#pragma unroll
      for (int n = 0; n < 4; n++)
        bfr[n] = *(const bf16x8*)&sB[(wn + n * 16 + lr) * 64 + kk * 32 + lg * 8];
#pragma unroll
      for (int m = 0; m < 4; m++)
#pragma unroll
        for (int n = 0; n < 4; n++)
          acc[m][n] = __builtin_amdgcn_mfma_f32_16x16x32_bf16(af[m], bfr[n], acc[m][n], 0, 0, 0);
    }
    __syncthreads();
  }
#pragma unroll
  for (int m = 0; m < 4; m++) {
#pragma unroll
    for (int n = 0; n < 4; n++) {
      long col = n0 + wn + n * 16 + lr;
#pragma unroll
      for (int j = 0; j < 4; j++) {
        long row = m0 + wm + m * 16 + lg * 4 + j;
        C[row * N + col] = acc[m][n][j];
      }
    }
  }
}

// ---------------- RMSNorm + RoPE + gain + pack to bf16 ----------------
// Q is additionally scaled by 0.125*log2(e) so attention scores are base-2 logits.
__global__ __launch_bounds__(256) void pack_kernel(
    const float* __restrict__ qkv, const float* __restrict__ tab,
    const float* __restrict__ qg,
    unsigned short* __restrict__ qb, unsigned short* __restrict__ kb,
    unsigned short* __restrict__ vtb) {
  const int wid = (blockIdx.x * 256 + threadIdx.x) >> 6;
  const int lane = threadIdx.x & 63;
  const int row = wid / 24;      // b*2048 + s
  const int u = wid % 24;
  const int b = row >> 11, s = row & 2047;
  float v;
  if (u < 16)      v = qkv[(size_t)row * 1536 + u * 64 + lane];
  else if (u < 20) v = qkv[(size_t)row * 1536 + 1024 + (u - 16) * 64 + lane];
  else             v = qkv[(size_t)row * 1536 + 1280 + (u - 20) * 64 + lane];
  if (u < 20) {
    float ss = v * v;
#pragma unroll
    for (int m = 32; m >= 1; m >>= 1) ss += __shfl_xor(ss, m);
    float n = v * rsqrtf(ss * (1.0f / 64.0f) + 1.1920929e-07f);
    int i = lane & 31;
    float c = tab[s * 64 + i], sn = tab[s * 64 + 32 + i];
    float p = __shfl_xor(n, 32);
    float o = (lane < 32) ? (n * c + p * sn) : (n * c - p * sn);
    if (u < 16) {
      o *= qg[u] * (0.125f * LOG2E);
      qb[((size_t)(b * 16 + u) * 2048 + s) * 64 + lane] = f2bf(o);
    } else {
      kb[((size_t)(b * 4 + (u - 16)) * 2048 + s) * 64 + lane] = f2bf(o);
    }
  } else {
    int hk = u - 20;
    vtb[((size_t)(b * 4 + hk) * 64 + lane) * 2048 + s] = f2bf(v);  // V^T [64][S]
  }
}

// ---------------- causal flash attention, KVBLK=64, double-buffered LDS ----------------
// block = 4 waves = 64 q rows of one (b,h); wave w owns rows q0=qt*64+w*16 .. +15.
// Swapped QK^T (mfma(K,Q)) -> S^T lane-local; PV via 16x16x16 (Y^T = V^T * P^T), no shuffles.
// LDS tiles XOR-swizzled (chunk ^= row&7) on source AND read (rule 21).
__global__ __launch_bounds__(256) void attn_kernel(
    const unsigned short* __restrict__ qb, const unsigned short* __restrict__ kb,
    const unsigned short* __restrict__ vtb, unsigned short* __restrict__ yb) {
  __shared__ unsigned short sK[2][64 * 64];
  __shared__ unsigned short sV[2][64 * 64];
  const int tid = threadIdx.x;
  const int lane = tid & 63;
  const int w = tid >> 6;
  const int qt = 31 - (blockIdx.x >> 5);   // heavy-first dispatch
  const int bh = blockIdx.x & 31;
  const int h = bh & 15;
  const int b = bh >> 4;
  const int q0 = qt * 64 + w * 16;
  const unsigned short* Q = qb + (size_t)(b * 16 + h) * 2048 * 64;
  const unsigned short* K = kb + (size_t)(b * 4 + (h >> 2)) * 2048 * 64;
  const unsigned short* V = vtb + (size_t)(b * 4 + (h >> 2)) * 64 * 2048;
  const int qc = lane & 15;
  const int g = lane >> 4;
  const int qrow = q0 + qc;
  const bf16x8 qf0 = *(const bf16x8*)(Q + (size_t)qrow * 64 + g * 8);
  const bf16x8 qf1 = *(const bf16x8*)(Q + (size_t)qrow * 64 + 32 + g * 8);
  f32x4 acc[4];
  acc[0] = acc[1] = acc[2] = acc[3] = (f32x4){0.f, 0.f, 0.f, 0.f};
  float m_run = -1e30f, l_run = 0.f;
  const int nt = qt + 1;

  // stage tile 0 into buf 0 (K: chunks 0..511, V: 512..1023; 4 gload16/thread)
  {
    const int kv0 = 0;
#pragma unroll
    for (int i = 0; i < 2; i++) {
      int chunk = i * 256 + tid;
      int r = chunk >> 3, c = chunk & 7;
      gload16(K + (size_t)(kv0 + r) * 64 + ((c ^ (r & 7)) << 3), (char*)&sK[0][0] + chunk * 16);
    }
#pragma unroll
    for (int i = 0; i < 2; i++) {
      int chunk = i * 256 + tid;
      int r = chunk >> 3, c = chunk & 7;
      gload16(V + (size_t)r * 2048 + kv0 + ((c ^ (r & 7)) << 3), (char*)&sV[0][0] + chunk * 16);
    }
  }
  int cur = 0;
  for (int t = 0; t < nt; ++t) {
    __syncthreads();   // implicit vmcnt(0): buf[cur] ready; buf[cur^1] free to overwrite
    if (t + 1 < nt) {  // prefetch next tile into buf[cur^1], stays in flight across compute
      const int kv0 = (t + 1) << 6;
      const int nb = cur ^ 1;
#pragma unroll
      for (int i = 0; i < 2; i++) {
        int chunk = i * 256 + tid;
        int r = chunk >> 3, c = chunk & 7;
        gload16(K + (size_t)(kv0 + r) * 64 + ((c ^ (r & 7)) << 3), (char*)&sK[nb][0] + chunk * 16);
      }
#pragma unroll
      for (int i = 0; i < 2; i++) {
        int chunk = i * 256 + tid;
        int r = chunk >> 3, c = chunk & 7;
        gload16(V + (size_t)r * 2048 + kv0 + ((c ^ (r & 7)) << 3), (char*)&sV[nb][0] + chunk * 16);
      }
    }
    // ---- QK^T: 4 sub-tiles of 16 kv ----
    float s[4][4];
#pragma unroll
    for (int ks = 0; ks < 4; ++ks) {
      const int r = ks * 16 + qc;
      bf16x8 kf0 = *(const bf16x8*)&sK[cur][r * 64 + ((g ^ (r & 7)) << 3)];
      bf16x8 kf1 = *(const bf16x8*)&sK[cur][r * 64 + (((4 + g) ^ (r & 7)) << 3)];
      f32x4 st = (f32x4){0.f, 0.f, 0.f, 0.f};
      st = __builtin_amdgcn_mfma_f32_16x16x32_bf16(kf0, qf0, st, 0, 0, 0);
      st = __builtin_amdgcn_mfma_f32_16x16x32_bf16(kf1, qf1, st, 0, 0, 0);
#pragma unroll
      for (int j = 0; j < 4; ++j) s[ks][j] = st[j];
    }
    if (t == nt - 1) {  // diagonal tile: mask kv > qrow (within-tile indices)
#pragma unroll
      for (int ks = 0; ks < 4; ++ks)
#pragma unroll
        for (int j = 0; j < 4; ++j)
          if (ks * 16 + g * 4 + j > w * 16 + qc) s[ks][j] = -1e30f;
    }
    // ---- online softmax over 64 kv (base-2 logits) ----
    float mt = -1e30f;
#pragma unroll
    for (int ks = 0; ks < 4; ++ks)
#pragma unroll
      for (int j = 0; j < 4; ++j) mt = fmaxf(mt, s[ks][j]);
    mt = fmaxf(mt, __shfl_xor(mt, 16));
    mt = fmaxf(mt, __shfl_xor(mt, 32));
    const float m_new = fmaxf(m_run, mt);
    const float corr = exp2f(m_run - m_new);
    float p[4][4], ts = 0.f;
#pragma unroll
    for (int ks = 0; ks < 4; ++ks)
#pragma unroll
      for (int j = 0; j < 4; ++j) { p[ks][j] = exp2f(s[ks][j] - m_new); ts += p[ks][j]; }
    ts += __shfl_xor(ts, 16);
    ts += __shfl_xor(ts, 32);
    l_run = l_run * corr + ts;
    m_run = m_new;
    short4v pb[4];
#pragma unroll
    for (int ks = 0; ks < 4; ++ks)
#pragma unroll
      for (int j = 0; j < 4; ++j) pb[ks][j] = bfbits(p[ks][j]);
#pragma unroll
    for (int d = 0; d < 4; ++d)
#pragma unroll
      for (int j = 0; j < 4; ++j) acc[d][j] *= corr;
    // ---- PV: Y^T += V^T * P^T, 16x16x16 per (ks,d) ----
#pragma unroll
    for (int ks = 0; ks < 4; ++ks) {
#pragma unroll
      for (int d = 0; d < 4; ++d) {
        const int rd = d * 16 + qc;
        const int el = rd * 64 + ((((ks * 2 + (g >> 1)) ^ (rd & 7)) << 3) + ((g & 1) << 2));
        short4v vf = *(const short4v*)&sV[cur][el];
        acc[d] = __builtin_amdgcn_mfma_f32_16x16x16bf16_1k(vf, pb[ks], acc[d], 0, 0, 0);
      }
    }
    cur ^= 1;
  }
  const float inv = 1.0f / l_run;
  unsigned short* Y = yb + (size_t)(b * 2048 + qrow) * 1024 + h * 64;
#pragma unroll
  for (int d = 0; d < 4; ++d)
#pragma unroll
    for (int j = 0; j < 4; ++j)
      Y[d * 16 + g * 4 + j] = (unsigned short)(unsigned short)bfbits(acc[d][j] * inv);
}

extern "C" void kernel_launch(void* const* d_in, const int* in_sizes, int n_in,
                              void* d_out, int out_size, void* d_ws, size_t ws_size,
                              hipStream_t stream) {
  const float* x  = (const float*)d_in[0];
  const float* Wq = (const float*)d_in[1];
  const float* Wk = (const float*)d_in[2];
  const float* Wv = (const float*)d_in[3];
  const float* Wo = (const float*)d_in[4];
  const float* qg = (const float*)d_in[5];
  float* out = (float*)d_out;

  char* ws = (char*)d_ws;
  const size_t NEED = 60293120;
  if (ws_size < NEED) return;
  unsigned short* xb   = (unsigned short*)(ws);                 // 8,388,608
  unsigned short* wqkv = (unsigned short*)(ws + 8388608);       // 3,145,728
  unsigned short* wo_b = (unsigned short*)(ws + 11534336);      // 2,097,152
  float*          qkvf = (float*)        (ws + 13631488);       // 25,165,824
  unsigned short* qbuf = (unsigned short*)(ws + 38797312);      // 8,388,608
  unsigned short* kbuf = (unsigned short*)(ws + 47185920);      // 2,097,152
  unsigned short* vtb  = (unsigned short*)(ws + 49283072);      // 2,097,152
  unsigned short* ybuf = (unsigned short*)(ws + 51380224);      // 8,388,608
  float*          tab  = (float*)        (ws + 59768832);       // 524,288

  cast4_kernel<<<4096, 256, 0, stream>>>(x, xb, 1048576);
  cast4_kernel<<<1024, 256, 0, stream>>>(Wq, wqkv, 262144);
  cast4_kernel<<<256, 256, 0, stream>>>(Wk, wqkv + 1048576, 65536);
  cast4_kernel<<<256, 256, 0, stream>>>(Wv, wqkv + 1310720, 65536);
  cast4_kernel<<<1024, 256, 0, stream>>>(Wo, wo_b, 262144);
  tab_kernel<<<256, 256, 0, stream>>>(tab);
  gemm_bt_kernel<<<32 * 12, 256, 0, stream>>>(xb, wqkv, qkvf, 4096, 1536, 1024, 12);
  pack_kernel<<<24576, 256, 0, stream>>>(qkvf, tab, qg, qbuf, kbuf, vtb);
  attn_kernel<<<1024, 256, 0, stream>>>(qbuf, kbuf, vtb, ybuf);
  gemm_bt_kernel<<<32 * 8, 256, 0, stream>>>(ybuf, wo_b, out, 4096, 1024, 1024, 8);
}

// Round 4
// 129.511 us; speedup vs baseline: 3.2655x; 1.0821x over previous
//
#include <hip/hip_runtime.h>
#include <hip/hip_bf16.h>
#include <math.h>

typedef __attribute__((ext_vector_type(8))) __bf16 bf16x8;
typedef __attribute__((ext_vector_type(4))) short short4v;
typedef __attribute__((ext_vector_type(4))) float f32x4;
typedef __attribute__((ext_vector_type(4))) unsigned short ushort4v;

#define LOG2E 1.44269504088896340736f

static __device__ __forceinline__ unsigned short f2bf(float f) {
  unsigned int u = __float_as_uint(f);
  return (unsigned short)((u + 0x7fffu + ((u >> 16) & 1u)) >> 16);
}
static __device__ __forceinline__ short bfbits(float f) {
  __bf16 h = (__bf16)f;
  return __builtin_bit_cast(short, h);
}

static __device__ __forceinline__ void gload16(const unsigned short* g, void* l) {
  __builtin_amdgcn_global_load_lds(
      (const __attribute__((address_space(1))) unsigned int*)g,
      (__attribute__((address_space(3))) unsigned int*)l, 16, 0, 0);
}

// ---------------- fused prep: all casts + RoPE table in one launch ----------------
__global__ __launch_bounds__(256) void prep_kernel(
    const float* __restrict__ x, const float* __restrict__ Wq,
    const float* __restrict__ Wk, const float* __restrict__ Wv,
    const float* __restrict__ Wo,
    unsigned short* __restrict__ xb, unsigned short* __restrict__ wqkv,
    unsigned short* __restrict__ wo_b, float* __restrict__ tab) {
  const int bx = blockIdx.x, tid = threadIdx.x;
  if (bx < 6656) {  // cast regions
    const float* src;
    unsigned short* dst;
    int i;
    if (bx < 4096)       { src = x;  dst = xb;             i = bx * 256 + tid; }
    else if (bx < 5120)  { src = Wq; dst = wqkv;           i = (bx - 4096) * 256 + tid; }
    else if (bx < 5376)  { src = Wk; dst = wqkv + 1048576; i = (bx - 5120) * 256 + tid; }
    else if (bx < 5632)  { src = Wv; dst = wqkv + 1310720; i = (bx - 5376) * 256 + tid; }
    else                 { src = Wo; dst = wo_b;           i = (bx - 5632) * 256 + tid; }
    float4 v = reinterpret_cast<const float4*>(src)[i];
    ushort4v o;
    o.x = f2bf(v.x); o.y = f2bf(v.y); o.z = f2bf(v.z); o.w = f2bf(v.w);
    reinterpret_cast<ushort4v*>(dst)[i] = o;
  } else {          // RoPE table: 256 blocks
    int i = (bx - 6656) * 256 + tid;  // 65536 = 2048*32
    int s = i >> 5, d = i & 31;
    float invf = powf(10000.f, -(float)d / 32.f);
    float fr = (float)s * invf;
    tab[s * 64 + d] = cosf(fr);
    tab[s * 64 + 32 + d] = sinf(fr);
  }
}

// ---------------- bf16 GEMM: C[M,N] f32 = A[M,K] * B[N,K]^T ----------------
__global__ __launch_bounds__(256) void gemm_bt_kernel(
    const unsigned short* __restrict__ A, const unsigned short* __restrict__ B,
    float* __restrict__ C, int M, int N, int K, int nbn) {
  __shared__ unsigned short sA[128 * 64];
  __shared__ unsigned short sB[128 * 64];
  const int t = threadIdx.x;
  const int lane = t & 63;
  const int w = t >> 6;
  const int bm = blockIdx.x / nbn, bn = blockIdx.x % nbn;
  const long m0 = (long)bm * 128, n0 = (long)bn * 128;
  const int wm = (w >> 1) * 64, wn = (w & 1) * 64;
  const int lr = lane & 15, lg = lane >> 4;
  f32x4 acc[4][4];
#pragma unroll
  for (int i = 0; i < 4; i++)
#pragma unroll
    for (int j = 0; j < 4; j++) acc[i][j] = (f32x4){0.f, 0.f, 0.f, 0.f};

  for (int k0 = 0; k0 < K; k0 += 64) {
#pragma unroll
    for (int i = 0; i < 4; i++) {
      int chunk = i * 256 + t;
      int r = chunk >> 3;
      int c = (chunk & 7) << 3;
      gload16(A + (m0 + r) * (long)K + k0 + c, (char*)sA + chunk * 16);
      gload16(B + (n0 + r) * (long)K + k0 + c, (char*)sB + chunk * 16);
    }
    __syncthreads();
#pragma unroll
    for (int kk = 0; kk < 2; ++kk) {
      bf16x8 af[4], bfr[4];
#pragma unroll
      for (int m = 0; m < 4; m++)
        af[m] = *(const bf16x8*)&sA[(wm + m * 16 + lr) * 64 + kk * 32 + lg * 8];
#pragma unroll
      for (int n = 0; n < 4; n++)
        bfr[n] = *(const bf16x8*)&sB[(wn + n * 16 + lr) * 64 + kk * 32 + lg * 8];
#pragma unroll
      for (int m = 0; m < 4; m++)
#pragma unroll
        for (int n = 0; n < 4; n++)
          acc[m][n] = __builtin_amdgcn_mfma_f32_16x16x32_bf16(af[m], bfr[n], acc[m][n], 0, 0, 0);
    }
    __syncthreads();
  }
#pragma unroll
  for (int m = 0; m < 4; m++) {
#pragma unroll
    for (int n = 0; n < 4; n++) {
      long col = n0 + wn + n * 16 + lr;
#pragma unroll
      for (int j = 0; j < 4; j++) {
        long row = m0 + wm + m * 16 + lg * 4 + j;
        C[row * N + col] = acc[m][n][j];
      }
    }
  }
}

// ---------------- RMSNorm + RoPE + gain + pack to bf16 ----------------
// Q additionally scaled by 0.125*log2(e): attention scores become base-2 logits.
__global__ __launch_bounds__(256) void pack_kernel(
    const float* __restrict__ qkv, const float* __restrict__ tab,
    const float* __restrict__ qg,
    unsigned short* __restrict__ qb, unsigned short* __restrict__ kb,
    unsigned short* __restrict__ vtb) {
  const int wid = (blockIdx.x * 256 + threadIdx.x) >> 6;
  const int lane = threadIdx.x & 63;
  const int row = wid / 24;      // b*2048 + s
  const int u = wid % 24;
  const int b = row >> 11, s = row & 2047;
  float v;
  if (u < 16)      v = qkv[(size_t)row * 1536 + u * 64 + lane];
  else if (u < 20) v = qkv[(size_t)row * 1536 + 1024 + (u - 16) * 64 + lane];
  else             v = qkv[(size_t)row * 1536 + 1280 + (u - 20) * 64 + lane];
  if (u < 20) {
    float ss = v * v;
#pragma unroll
    for (int m = 32; m >= 1; m >>= 1) ss += __shfl_xor(ss, m);
    float n = v * rsqrtf(ss * (1.0f / 64.0f) + 1.1920929e-07f);
    int i = lane & 31;
    float c = tab[s * 64 + i], sn = tab[s * 64 + 32 + i];
    float p = __shfl_xor(n, 32);
    float o = (lane < 32) ? (n * c + p * sn) : (n * c - p * sn);
    if (u < 16) {
      o *= qg[u] * (0.125f * LOG2E);
      qb[((size_t)(b * 16 + u) * 2048 + s) * 64 + lane] = f2bf(o);
    } else {
      kb[((size_t)(b * 4 + (u - 16)) * 2048 + s) * 64 + lane] = f2bf(o);
    }
  } else {
    int hk = u - 20;
    vtb[((size_t)(b * 4 + hk) * 64 + lane) * 2048 + s] = f2bf(v);  // V^T [64][S]
  }
}

// ---------------- causal flash attention, KVBLK=64, double-buffered LDS ----------------
// Fixed-max softmax: after RMSNorm |q̂|=|k̂|=8, so s (base-2 logit) is bounded by
// 11.6*|g|; use static M = 11.7*|qg[h]| -> no online max, no rescale, per-lane l-sum.
__global__ __launch_bounds__(256) void attn_kernel(
    const unsigned short* __restrict__ qb, const unsigned short* __restrict__ kb,
    const unsigned short* __restrict__ vtb, unsigned short* __restrict__ yb,
    const float* __restrict__ qg) {
  __shared__ unsigned short sK[2][64 * 64];
  __shared__ unsigned short sV[2][64 * 64];
  const int tid = threadIdx.x;
  const int lane = tid & 63;
  const int w = tid >> 6;
  const int qt = 31 - (blockIdx.x >> 5);   // heavy-first dispatch
  const int bh = blockIdx.x & 31;
  const int h = bh & 15;
  const int b = bh >> 4;
  const float M = 11.7f * fabsf(qg[h]);
  const int q0 = qt * 64 + w * 16;
  const unsigned short* Q = qb + (size_t)(b * 16 + h) * 2048 * 64;
  const unsigned short* K = kb + (size_t)(b * 4 + (h >> 2)) * 2048 * 64;
  const unsigned short* V = vtb + (size_t)(b * 4 + (h >> 2)) * 64 * 2048;
  const int qc = lane & 15;
  const int g = lane >> 4;
  const int qrow = q0 + qc;
  const bf16x8 qf0 = *(const bf16x8*)(Q + (size_t)qrow * 64 + g * 8);
  const bf16x8 qf1 = *(const bf16x8*)(Q + (size_t)qrow * 64 + 32 + g * 8);
  f32x4 acc[4];
  acc[0] = acc[1] = acc[2] = acc[3] = (f32x4){0.f, 0.f, 0.f, 0.f};
  float lsum = 0.f;
  const int nt = qt + 1;

  {  // stage tile 0 into buf 0
#pragma unroll
    for (int i = 0; i < 2; i++) {
      int chunk = i * 256 + tid;
      int r = chunk >> 3, c = chunk & 7;
      gload16(K + (size_t)r * 64 + ((c ^ (r & 7)) << 3), (char*)&sK[0][0] + chunk * 16);
    }
#pragma unroll
    for (int i = 0; i < 2; i++) {
      int chunk = i * 256 + tid;
      int r = chunk >> 3, c = chunk & 7;
      gload16(V + (size_t)r * 2048 + ((c ^ (r & 7)) << 3), (char*)&sV[0][0] + chunk * 16);
    }
  }
  int cur = 0;
  for (int t = 0; t < nt; ++t) {
    __syncthreads();   // drains vmcnt: buf[cur] ready; prior compute on buf[cur^1] done
    if (t + 1 < nt) {  // prefetch next tile; stays in flight across this compute phase
      const int kv0 = (t + 1) << 6;
      const int nb = cur ^ 1;
#pragma unroll
      for (int i = 0; i < 2; i++) {
        int chunk = i * 256 + tid;
        int r = chunk >> 3, c = chunk & 7;
        gload16(K + (size_t)(kv0 + r) * 64 + ((c ^ (r & 7)) << 3), (char*)&sK[nb][0] + chunk * 16);
      }
#pragma unroll
      for (int i = 0; i < 2; i++) {
        int chunk = i * 256 + tid;
        int r = chunk >> 3, c = chunk & 7;
        gload16(V + (size_t)r * 2048 + kv0 + ((c ^ (r & 7)) << 3), (char*)&sV[nb][0] + chunk * 16);
      }
    }
    // ---- QK^T: 4 sub-tiles of 16 kv ----
    f32x4 st[4];
    __builtin_amdgcn_s_setprio(1);
#pragma unroll
    for (int ks = 0; ks < 4; ++ks) {
      const int r = ks * 16 + qc;
      bf16x8 kf0 = *(const bf16x8*)&sK[cur][r * 64 + ((g ^ (r & 7)) << 3)];
      bf16x8 kf1 = *(const bf16x8*)&sK[cur][r * 64 + (((4 + g) ^ (r & 7)) << 3)];
      f32x4 a = (f32x4){0.f, 0.f, 0.f, 0.f};
      a = __builtin_amdgcn_mfma_f32_16x16x32_bf16(kf0, qf0, a, 0, 0, 0);
      a = __builtin_amdgcn_mfma_f32_16x16x32_bf16(kf1, qf1, a, 0, 0, 0);
      st[ks] = a;
    }
    __builtin_amdgcn_s_setprio(0);
    if (t == nt - 1) {  // diagonal tile: mask kv > qrow (within-tile indices)
#pragma unroll
      for (int ks = 0; ks < 4; ++ks)
#pragma unroll
        for (int j = 0; j < 4; ++j)
          if (ks * 16 + g * 4 + j > w * 16 + qc) st[ks][j] = -1e30f;
    }
    // ---- fixed-max softmax: p = exp2(s - M), per-lane l accumulation ----
    short4v pb[4];
#pragma unroll
    for (int ks = 0; ks < 4; ++ks)
#pragma unroll
      for (int j = 0; j < 4; ++j) {
        float p = exp2f(st[ks][j] - M);
        lsum += p;
        pb[ks][j] = bfbits(p);
      }
    // ---- PV: Y^T += V^T * P^T ----
    __builtin_amdgcn_s_setprio(1);
#pragma unroll
    for (int ks = 0; ks < 4; ++ks) {
#pragma unroll
      for (int d = 0; d < 4; ++d) {
        const int rd = d * 16 + qc;
        const int el = rd * 64 + ((((ks * 2 + (g >> 1)) ^ (rd & 7)) << 3) + ((g & 1) << 2));
        short4v vf = *(const short4v*)&sV[cur][el];
        acc[d] = __builtin_amdgcn_mfma_f32_16x16x16bf16_1k(vf, pb[ks], acc[d], 0, 0, 0);
      }
    }
    __builtin_amdgcn_s_setprio(0);
    cur ^= 1;
  }
  float l = lsum;
  l += __shfl_xor(l, 16);
  l += __shfl_xor(l, 32);
  const float inv = 1.0f / l;
  unsigned short* Y = yb + (size_t)(b * 2048 + qrow) * 1024 + h * 64;
#pragma unroll
  for (int d = 0; d < 4; ++d)
#pragma unroll
    for (int j = 0; j < 4; ++j)
      Y[d * 16 + g * 4 + j] = (unsigned short)bfbits(acc[d][j] * inv);
}

extern "C" void kernel_launch(void* const* d_in, const int* in_sizes, int n_in,
                              void* d_out, int out_size, void* d_ws, size_t ws_size,
                              hipStream_t stream) {
  const float* x  = (const float*)d_in[0];
  const float* Wq = (const float*)d_in[1];
  const float* Wk = (const float*)d_in[2];
  const float* Wv = (const float*)d_in[3];
  const float* Wo = (const float*)d_in[4];
  const float* qg = (const float*)d_in[5];
  float* out = (float*)d_out;

  char* ws = (char*)d_ws;
  const size_t NEED = 60293120;
  if (ws_size < NEED) return;
  unsigned short* xb   = (unsigned short*)(ws);                 // 8,388,608
  unsigned short* wqkv = (unsigned short*)(ws + 8388608);       // 3,145,728
  unsigned short* wo_b = (unsigned short*)(ws + 11534336);      // 2,097,152
  float*          qkvf = (float*)        (ws + 13631488);       // 25,165,824
  unsigned short* qbuf = (unsigned short*)(ws + 38797312);      // 8,388,608
  unsigned short* kbuf = (unsigned short*)(ws + 47185920);      // 2,097,152
  unsigned short* vtb  = (unsigned short*)(ws + 49283072);      // 2,097,152
  unsigned short* ybuf = (unsigned short*)(ws + 51380224);      // 8,388,608
  float*          tab  = (float*)        (ws + 59768832);       // 524,288

  prep_kernel<<<6912, 256, 0, stream>>>(x, Wq, Wk, Wv, Wo, xb, wqkv, wo_b, tab);
  gemm_bt_kernel<<<32 * 12, 256, 0, stream>>>(xb, wqkv, qkvf, 4096, 1536, 1024, 12);
  pack_kernel<<<24576, 256, 0, stream>>>(qkvf, tab, qg, qbuf, kbuf, vtb);
  attn_kernel<<<1024, 256, 0, stream>>>(qbuf, kbuf, vtb, ybuf, qg);
  gemm_bt_kernel<<<32 * 8, 256, 0, stream>>>(ybuf, wo_b, out, 4096, 1024, 1024, 8);
}